// Round 1
// baseline (144.662 us; speedup 1.0000x reference)
//
#include <hip/hip_runtime.h>
#include <hip/hip_bf16.h>

#define BB  4
#define LL  256
#define DD  256
#define HH  8
#define DHH 32
#define BL  1024   // B*L

// ---------------------------------------------------------------------------
// Mask dtype auto-detection.
// jax bool mask may arrive as u8 (raw numpy bool), int32, or float32.
// Scan first 64KB as u32 words:
//   - float32 {0.0,1.0}: some word == 0x3F800000
//   - u8 bool bytes:     some nonzero byte at position %4 != 0 (hi bytes)
//   - int32 {0,1}:       neither
// flags[0] = 1 if elements are 4-byte, 0 if 1-byte.
// ---------------------------------------------------------------------------
__global__ __launch_bounds__(1024) void mask_detect_kernel(
    const unsigned int* __restrict__ w, unsigned int* __restrict__ flags) {
  __shared__ int sf32, shib;
  const int t = threadIdx.x;
  if (t == 0) { sf32 = 0; shib = 0; }
  __syncthreads();
  int f = 0, hb = 0;
  for (int i = t; i < 16384; i += 1024) {
    unsigned int x = w[i];
    if (x == 0x3F800000u) f = 1;
    else if (x & 0xFFFFFF00u) hb = 1;
  }
  if (f)  atomicOr(&sf32, 1);
  if (hb) atomicOr(&shib, 1);
  __syncthreads();
  if (t == 0) flags[0] = (sf32 || !shib) ? 1u : 0u;
}

// ---------------------------------------------------------------------------
// Fused QKV projection: qu = Xq/sqrt(DH)+u, qv = Xq/sqrt(DH)+v, K, V.
// Block = 4 rows x all 256 cols; thread t = output col t.
// W rows are contiguous (X @ W.T), X rows broadcast across the block.
// ---------------------------------------------------------------------------
__global__ __launch_bounds__(256) void qkv_kernel(
    const float* __restrict__ X,
    const float* __restrict__ Wq, const float* __restrict__ bq,
    const float* __restrict__ Wk, const float* __restrict__ bk,
    const float* __restrict__ Wv, const float* __restrict__ bv,
    const float* __restrict__ u,  const float* __restrict__ vp,
    float* __restrict__ qu, float* __restrict__ qv,
    float* __restrict__ K,  float* __restrict__ V) {
  const int row0 = blockIdx.x * 4;
  const int c = threadIdx.x;
  float accq[4] = {0.f, 0.f, 0.f, 0.f};
  float acck[4] = {0.f, 0.f, 0.f, 0.f};
  float accv[4] = {0.f, 0.f, 0.f, 0.f};
  const float4* Wq4 = (const float4*)(Wq + c * DD);
  const float4* Wk4 = (const float4*)(Wk + c * DD);
  const float4* Wv4 = (const float4*)(Wv + c * DD);
  const float4* X4  = (const float4*)X;
  const int xbase = row0 * (DD / 4);
#pragma unroll 8
  for (int j4 = 0; j4 < DD / 4; ++j4) {
    const float4 wq = Wq4[j4], wk = Wk4[j4], wv = Wv4[j4];
#pragma unroll
    for (int r = 0; r < 4; ++r) {
      const float4 x = X4[xbase + r * (DD / 4) + j4];
      accq[r] += x.x * wq.x + x.y * wq.y + x.z * wq.z + x.w * wq.w;
      acck[r] += x.x * wk.x + x.y * wk.y + x.z * wk.z + x.w * wk.w;
      accv[r] += x.x * wv.x + x.y * wv.y + x.z * wv.z + x.w * wv.w;
    }
  }
  const float scale = 0.17677669529663687f;  // 1/sqrt(32)
  const float uc = u[c], vc = vp[c], bqc = bq[c], bkc = bk[c], bvc = bv[c];
#pragma unroll
  for (int r = 0; r < 4; ++r) {
    const int idx = (row0 + r) * DD + c;
    const float pq = (accq[r] + bqc) * scale;
    qu[idx] = pq + uc;
    qv[idx] = pq + vc;
    K[idx]  = acck[r] + bkc;
    V[idx]  = accv[r] + bvc;
  }
}

// ---------------------------------------------------------------------------
// Main attention kernel. One block per (b,q); thread t = key position k.
// Streams rel[b,q,k,:] (1KB/thread, the 256MiB dominant traffic) and K rows,
// computes 8 head scores per thread, block softmax, then ctx = attn @ V.
// ---------------------------------------------------------------------------
__global__ __launch_bounds__(256) void attn_kernel(
    const float* __restrict__ qu, const float* __restrict__ qv,
    const float* __restrict__ Km, const float* __restrict__ Vm,
    const float* __restrict__ rel, const void* __restrict__ mask_raw,
    const unsigned int* __restrict__ flags,
    float* __restrict__ attn_out, float* __restrict__ ctx) {
  const int bq = blockIdx.x;
  const int b = bq >> 8, q = bq & 255;
  const int t = threadIdx.x;
  __shared__ float qu_s[DD], qv_s[DD];
  __shared__ float sc[HH][LL];
  qu_s[t] = qu[bq * DD + t];
  qv_s[t] = qv[bq * DD + t];
  __syncthreads();

  bool masked;
  if (flags[0]) masked = ((const unsigned int*)mask_raw)[bq * LL + t] != 0u;
  else          masked = ((const unsigned char*)mask_raw)[bq * LL + t] != 0;

  const float4* K4  = (const float4*)(Km + (size_t)(b * LL + t) * DD);
  const float4* R4  = (const float4*)(rel + ((size_t)bq * LL + t) * DD);
  const float4* qu4 = (const float4*)qu_s;
  const float4* qv4 = (const float4*)qv_s;

#pragma unroll
  for (int h = 0; h < HH; ++h) {
    float a = 0.f;
#pragma unroll
    for (int j = 0; j < 8; ++j) {
      const int j4 = h * 8 + j;
      const float4 kk = K4[j4], rr = R4[j4];
      const float4 a4 = qu4[j4], b4 = qv4[j4];
      a += a4.x * kk.x + a4.y * kk.y + a4.z * kk.z + a4.w * kk.w;
      a += b4.x * rr.x + b4.y * rr.y + b4.z * rr.z + b4.w * rr.w;
    }
    sc[h][t] = masked ? -1e18f : a;
  }
  __syncthreads();

  // Softmax: wave w handles heads 2w and 2w+1; each head's 256 scores live
  // in one wave (4 values/lane) -> shfl_xor tree over 64 lanes.
  const int wave = t >> 6, lane = t & 63;
#pragma unroll
  for (int hh = 0; hh < 2; ++hh) {
    const int h = wave * 2 + hh;
    float v0 = sc[h][lane], v1 = sc[h][lane + 64];
    float v2 = sc[h][lane + 128], v3 = sc[h][lane + 192];
    float m = fmaxf(fmaxf(v0, v1), fmaxf(v2, v3));
#pragma unroll
    for (int off = 32; off >= 1; off >>= 1) m = fmaxf(m, __shfl_xor(m, off));
    float e0 = __expf(v0 - m), e1 = __expf(v1 - m);
    float e2 = __expf(v2 - m), e3 = __expf(v3 - m);
    float s = (e0 + e1) + (e2 + e3);
#pragma unroll
    for (int off = 32; off >= 1; off >>= 1) s += __shfl_xor(s, off);
    const float inv = 1.0f / s;
    e0 *= inv; e1 *= inv; e2 *= inv; e3 *= inv;
    sc[h][lane] = e0; sc[h][lane + 64] = e1;
    sc[h][lane + 128] = e2; sc[h][lane + 192] = e3;
    float* aout = attn_out + (((size_t)(b * HH + h) * LL + q) * LL);
    aout[lane] = e0; aout[lane + 64] = e1;
    aout[lane + 128] = e2; aout[lane + 192] = e3;
  }
  __syncthreads();

  // ctx[b,q,d] = sum_k attn[h(d)][k] * V[b,k,d]; thread t = d, coalesced V.
  const int h = t >> 5;
  const float* Vb = Vm + (size_t)b * LL * DD + t;
  float c0 = 0.f, c1 = 0.f, c2 = 0.f, c3 = 0.f;
#pragma unroll 4
  for (int k = 0; k < LL; k += 4) {
    c0 += sc[h][k + 0] * Vb[(size_t)(k + 0) * DD];
    c1 += sc[h][k + 1] * Vb[(size_t)(k + 1) * DD];
    c2 += sc[h][k + 2] * Vb[(size_t)(k + 2) * DD];
    c3 += sc[h][k + 3] * Vb[(size_t)(k + 3) * DD];
  }
  ctx[bq * DD + t] = (c0 + c1) + (c2 + c3);
}

// ---------------------------------------------------------------------------
// Output projection: out = ctx @ Wo.T + bo
// ---------------------------------------------------------------------------
__global__ __launch_bounds__(256) void outproj_kernel(
    const float* __restrict__ ctx, const float* __restrict__ Wo,
    const float* __restrict__ bo, float* __restrict__ out) {
  const int row0 = blockIdx.x * 4;
  const int c = threadIdx.x;
  float acc[4] = {0.f, 0.f, 0.f, 0.f};
  const float4* W4 = (const float4*)(Wo + c * DD);
  const float4* X4 = (const float4*)ctx;
  const int xbase = row0 * (DD / 4);
#pragma unroll 8
  for (int j4 = 0; j4 < DD / 4; ++j4) {
    const float4 w = W4[j4];
#pragma unroll
    for (int r = 0; r < 4; ++r) {
      const float4 x = X4[xbase + r * (DD / 4) + j4];
      acc[r] += x.x * w.x + x.y * w.y + x.z * w.z + x.w * w.w;
    }
  }
  const float boc = bo[c];
#pragma unroll
  for (int r = 0; r < 4; ++r) out[(row0 + r) * DD + c] = acc[r] + boc;
}

extern "C" void kernel_launch(void* const* d_in, const int* in_sizes, int n_in,
                              void* d_out, int out_size, void* d_ws, size_t ws_size,
                              hipStream_t stream) {
  (void)in_sizes; (void)n_in; (void)out_size; (void)ws_size;
  const float* X   = (const float*)d_in[0];
  const void*  msk = d_in[1];
  const float* rel = (const float*)d_in[2];
  const float* Wq  = (const float*)d_in[3];
  const float* bq  = (const float*)d_in[4];
  const float* Wk  = (const float*)d_in[5];
  const float* bk  = (const float*)d_in[6];
  const float* Wv  = (const float*)d_in[7];
  const float* bv  = (const float*)d_in[8];
  const float* Wo  = (const float*)d_in[9];
  const float* bo  = (const float*)d_in[10];
  const float* u   = (const float*)d_in[11];
  const float* vp  = (const float*)d_in[12];

  float* out  = (float*)d_out;
  float* attn = out + BL * DD;  // outputs: [out (B,L,D) | attn (B,H,L,L)]

  float* ws_f = (float*)d_ws;
  float* qu  = ws_f;
  float* qv  = qu + BL * DD;
  float* K   = qv + BL * DD;
  float* V   = K  + BL * DD;
  float* ctx = V  + BL * DD;
  unsigned int* flags = (unsigned int*)(ctx + BL * DD);

  mask_detect_kernel<<<1, 1024, 0, stream>>>((const unsigned int*)msk, flags);
  qkv_kernel<<<BL / 4, 256, 0, stream>>>(X, Wq, bq, Wk, bk, Wv, bv, u, vp,
                                         qu, qv, K, V);
  attn_kernel<<<BL, 256, 0, stream>>>(qu, qv, K, V, rel, msk, flags, attn, ctx);
  outproj_kernel<<<BL / 4, 256, 0, stream>>>(ctx, Wo, bo, out);
}

// Round 2
// 111.007 us; speedup vs baseline: 1.3032x; 1.3032x over previous
//
#include <hip/hip_runtime.h>
#include <hip/hip_bf16.h>

#define BB  4
#define LL  256
#define DD  256
#define HH  8
#define DHH 32
#define BL  1024   // B*L

// ---------------------------------------------------------------------------
// Mask dtype auto-detection (bool may arrive as u8, int32, or float32).
// Scan first 64KB as u32 words:
//   - float32 {0.0,1.0}: some word == 0x3F800000
//   - u8 bool bytes:     some nonzero byte at position %4 != 0 (hi bytes)
//   - int32 {0,1}:       neither
// flags[0] = 1 if elements are 4-byte, 0 if 1-byte.
// ---------------------------------------------------------------------------
__global__ __launch_bounds__(1024) void mask_detect_kernel(
    const unsigned int* __restrict__ w, unsigned int* __restrict__ flags) {
  __shared__ int sf32, shib;
  const int t = threadIdx.x;
  if (t == 0) { sf32 = 0; shib = 0; }
  __syncthreads();
  int f = 0, hb = 0;
  for (int i = t; i < 16384; i += 1024) {
    unsigned int x = w[i];
    if (x == 0x3F800000u) f = 1;
    else if (x & 0xFFFFFF00u) hb = 1;
  }
  if (f)  atomicOr(&sf32, 1);
  if (hb) atomicOr(&shib, 1);
  __syncthreads();
  if (t == 0) flags[0] = (sf32 || !shib) ? 1u : 0u;
}

// ---------------------------------------------------------------------------
// Fused QKV projection: qu = Xq/sqrt(DH)+u, qv = Xq/sqrt(DH)+v, K, V.
// Block = 4 rows x all 256 cols; thread t = output col t.
// ---------------------------------------------------------------------------
__global__ __launch_bounds__(256) void qkv_kernel(
    const float* __restrict__ X,
    const float* __restrict__ Wq, const float* __restrict__ bq,
    const float* __restrict__ Wk, const float* __restrict__ bk,
    const float* __restrict__ Wv, const float* __restrict__ bv,
    const float* __restrict__ u,  const float* __restrict__ vp,
    float* __restrict__ qu, float* __restrict__ qv,
    float* __restrict__ K,  float* __restrict__ V) {
  const int row0 = blockIdx.x * 4;
  const int c = threadIdx.x;
  float accq[4] = {0.f, 0.f, 0.f, 0.f};
  float acck[4] = {0.f, 0.f, 0.f, 0.f};
  float accv[4] = {0.f, 0.f, 0.f, 0.f};
  const float4* Wq4 = (const float4*)(Wq + c * DD);
  const float4* Wk4 = (const float4*)(Wk + c * DD);
  const float4* Wv4 = (const float4*)(Wv + c * DD);
  const float4* X4  = (const float4*)X;
  const int xbase = row0 * (DD / 4);
#pragma unroll 8
  for (int j4 = 0; j4 < DD / 4; ++j4) {
    const float4 wq = Wq4[j4], wk = Wk4[j4], wv = Wv4[j4];
#pragma unroll
    for (int r = 0; r < 4; ++r) {
      const float4 x = X4[xbase + r * (DD / 4) + j4];
      accq[r] += x.x * wq.x + x.y * wq.y + x.z * wq.z + x.w * wq.w;
      acck[r] += x.x * wk.x + x.y * wk.y + x.z * wk.z + x.w * wk.w;
      accv[r] += x.x * wv.x + x.y * wv.y + x.z * wv.z + x.w * wv.w;
    }
  }
  const float scale = 0.17677669529663687f;  // 1/sqrt(32)
  const float uc = u[c], vc = vp[c], bqc = bq[c], bkc = bk[c], bvc = bv[c];
#pragma unroll
  for (int r = 0; r < 4; ++r) {
    const int idx = (row0 + r) * DD + c;
    const float pq = (accq[r] + bqc) * scale;
    qu[idx] = pq + uc;
    qv[idx] = pq + vc;
    K[idx]  = acck[r] + bkc;
    V[idx]  = accv[r] + bvc;
  }
}

// ---------------------------------------------------------------------------
// Main attention kernel. One block per (b,q).
// Phase 1 (scores): each WAVE cooperatively reads one k-row of K and rel:
//   lane l reads float4 j4=l -> one fully-coalesced 1KB load per instruction.
//   Lane l's float4 belongs to head h = l>>3 (DH=32 floats = 8 float4), so an
//   8-lane shfl_xor(1,2,4) reduce yields score[h][k] directly.
// Phase 2: per-head softmax via 64-lane shfl tree.
// Phase 3: ctx = attn @ V, thread t = output d (coalesced V columns).
// ---------------------------------------------------------------------------
__global__ __launch_bounds__(256) void attn_kernel(
    const float* __restrict__ qu, const float* __restrict__ qv,
    const float* __restrict__ Km, const float* __restrict__ Vm,
    const float* __restrict__ rel, const void* __restrict__ mask_raw,
    const unsigned int* __restrict__ flags,
    float* __restrict__ attn_out, float* __restrict__ ctx) {
  const int bq = blockIdx.x;
  const int b = bq >> 8, q = bq & 255;
  const int t = threadIdx.x;
  const int wave = t >> 6, lane = t & 63;
  __shared__ float qu_s[DD], qv_s[DD];
  __shared__ float msk_s[LL];
  __shared__ float sc[HH][LL + 4];   // +4 pad: strided head-writes hit 8 banks

  qu_s[t] = qu[bq * DD + t];
  qv_s[t] = qv[bq * DD + t];
  bool masked;
  if (flags[0]) masked = ((const unsigned int*)mask_raw)[bq * LL + t] != 0u;
  else          masked = ((const unsigned char*)mask_raw)[bq * LL + t] != 0;
  msk_s[t] = masked ? 1.f : 0.f;
  __syncthreads();

  // ---- Phase 1: scores ----
  const float4 u4 = ((const float4*)qu_s)[lane];
  const float4 w4 = ((const float4*)qv_s)[lane];
  const int h_of_lane = lane >> 3;
  // wave handles k in [wave*64, wave*64+64)
  const float4* K4 = (const float4*)(Km + (size_t)b * LL * DD) +
                     (size_t)(wave * 64) * 64 + lane;
  const float4* R4 = (const float4*)(rel + (size_t)bq * LL * DD) +
                     (size_t)(wave * 64) * 64 + lane;
#pragma unroll 4
  for (int i = 0; i < 64; ++i) {
    const int k = wave * 64 + i;
    const float4 kk = K4[(size_t)i * 64];
    const float4 rr = R4[(size_t)i * 64];
    float s = u4.x * kk.x + u4.y * kk.y + u4.z * kk.z + u4.w * kk.w
            + w4.x * rr.x + w4.y * rr.y + w4.z * rr.z + w4.w * rr.w;
    s += __shfl_xor(s, 1);
    s += __shfl_xor(s, 2);
    s += __shfl_xor(s, 4);
    if ((lane & 7) == 0)
      sc[h_of_lane][k] = (msk_s[k] != 0.f) ? -1e18f : s;
  }
  __syncthreads();

  // ---- Phase 2: softmax (wave w handles heads 2w, 2w+1) ----
#pragma unroll
  for (int hh = 0; hh < 2; ++hh) {
    const int h = wave * 2 + hh;
    float v0 = sc[h][lane], v1 = sc[h][lane + 64];
    float v2 = sc[h][lane + 128], v3 = sc[h][lane + 192];
    float m = fmaxf(fmaxf(v0, v1), fmaxf(v2, v3));
#pragma unroll
    for (int off = 32; off >= 1; off >>= 1) m = fmaxf(m, __shfl_xor(m, off));
    float e0 = __expf(v0 - m), e1 = __expf(v1 - m);
    float e2 = __expf(v2 - m), e3 = __expf(v3 - m);
    float s = (e0 + e1) + (e2 + e3);
#pragma unroll
    for (int off = 32; off >= 1; off >>= 1) s += __shfl_xor(s, off);
    const float inv = 1.0f / s;
    e0 *= inv; e1 *= inv; e2 *= inv; e3 *= inv;
    sc[h][lane] = e0; sc[h][lane + 64] = e1;
    sc[h][lane + 128] = e2; sc[h][lane + 192] = e3;
    float* aout = attn_out + (((size_t)(b * HH + h) * LL + q) * LL);
    aout[lane] = e0; aout[lane + 64] = e1;
    aout[lane + 128] = e2; aout[lane + 192] = e3;
  }
  __syncthreads();

  // ---- Phase 3: ctx[b,q,d] = sum_k attn[h(d)][k] * V[b,k,d] ----
  const int h = t >> 5;
  const float* Vb = Vm + (size_t)b * LL * DD + t;
  float c0 = 0.f, c1 = 0.f, c2 = 0.f, c3 = 0.f;
#pragma unroll 4
  for (int k = 0; k < LL; k += 4) {
    c0 += sc[h][k + 0] * Vb[(size_t)(k + 0) * DD];
    c1 += sc[h][k + 1] * Vb[(size_t)(k + 1) * DD];
    c2 += sc[h][k + 2] * Vb[(size_t)(k + 2) * DD];
    c3 += sc[h][k + 3] * Vb[(size_t)(k + 3) * DD];
  }
  ctx[bq * DD + t] = (c0 + c1) + (c2 + c3);
}

// ---------------------------------------------------------------------------
// Output projection: out = ctx @ Wo.T + bo
// ---------------------------------------------------------------------------
__global__ __launch_bounds__(256) void outproj_kernel(
    const float* __restrict__ ctx, const float* __restrict__ Wo,
    const float* __restrict__ bo, float* __restrict__ out) {
  const int row0 = blockIdx.x * 4;
  const int c = threadIdx.x;
  float acc[4] = {0.f, 0.f, 0.f, 0.f};
  const float4* W4 = (const float4*)(Wo + c * DD);
  const float4* X4 = (const float4*)ctx;
  const int xbase = row0 * (DD / 4);
#pragma unroll 8
  for (int j4 = 0; j4 < DD / 4; ++j4) {
    const float4 w = W4[j4];
#pragma unroll
    for (int r = 0; r < 4; ++r) {
      const float4 x = X4[xbase + r * (DD / 4) + j4];
      acc[r] += x.x * w.x + x.y * w.y + x.z * w.z + x.w * w.w;
    }
  }
  const float boc = bo[c];
#pragma unroll
  for (int r = 0; r < 4; ++r) out[(row0 + r) * DD + c] = acc[r] + boc;
}

extern "C" void kernel_launch(void* const* d_in, const int* in_sizes, int n_in,
                              void* d_out, int out_size, void* d_ws, size_t ws_size,
                              hipStream_t stream) {
  (void)in_sizes; (void)n_in; (void)out_size; (void)ws_size;
  const float* X   = (const float*)d_in[0];
  const void*  msk = d_in[1];
  const float* rel = (const float*)d_in[2];
  const float* Wq  = (const float*)d_in[3];
  const float* bq  = (const float*)d_in[4];
  const float* Wk  = (const float*)d_in[5];
  const float* bk  = (const float*)d_in[6];
  const float* Wv  = (const float*)d_in[7];
  const float* bv  = (const float*)d_in[8];
  const float* Wo  = (const float*)d_in[9];
  const float* bo  = (const float*)d_in[10];
  const float* u   = (const float*)d_in[11];
  const float* vp  = (const float*)d_in[12];

  float* out  = (float*)d_out;
  float* attn = out + BL * DD;  // outputs: [out (B,L,D) | attn (B,H,L,L)]

  float* ws_f = (float*)d_ws;
  float* qu  = ws_f;
  float* qv  = qu + BL * DD;
  float* K   = qv + BL * DD;
  float* V   = K  + BL * DD;
  float* ctx = V  + BL * DD;
  unsigned int* flags = (unsigned int*)(ctx + BL * DD);

  mask_detect_kernel<<<1, 1024, 0, stream>>>((const unsigned int*)msk, flags);
  qkv_kernel<<<BL / 4, 256, 0, stream>>>(X, Wq, bq, Wk, bk, Wv, bv, u, vp,
                                         qu, qv, K, V);
  attn_kernel<<<BL, 256, 0, stream>>>(qu, qv, K, V, rel, msk, flags, attn, ctx);
  outproj_kernel<<<BL / 4, 256, 0, stream>>>(ctx, Wo, bo, out);
}